// Round 1
// baseline (469.951 us; speedup 1.0000x reference)
//
#include <hip/hip_runtime.h>
#include <math.h>

// R1 baseline: correct fp32 pipeline, 7 dispatches.
// Workspace layout (floats): xp[4*66*66*256] | x1[16384*256] | offs[16384*288]
//                            | mlog[16384*144] | samp[16384*256]

#define HIN 66
#define WIN 66

// ---------------- zero xp (padded border must be 0; ws is poisoned 0xAA) ----
__global__ __launch_bounds__(256) void zero_f4(float4* __restrict__ p, int n) {
  int i = blockIdx.x * 256 + threadIdx.x;
  if (i < n) p[i] = make_float4(0.f, 0.f, 0.f, 0.f);
}

// ---------------- GEMM: C[16384 x Ncols] = A[16384 x 256] * B[256 x Ncols] + bias
// AMODE 0: A row-major [pix][k]. AMODE 1: A[p][k] = x[n][k][h][w] (NCHW source).
// CMODE 0: row-major C. CMODE 1: padded NHWC xp (write interior, +1 ring).
// CMODE 2: NCHW out (LDS-transpose epilogue for coalesced stores).
template<int AMODE, int CMODE>
__global__ __launch_bounds__(256) void gemm_k(
    const float* __restrict__ A, const float* __restrict__ B,
    const float* __restrict__ bias, float* __restrict__ C, int Ncols)
{
  __shared__ __align__(16) float As[32][132];
  __shared__ __align__(16) float Bs[32][132];
  const int t = threadIdx.x;
  const int bn = blockIdx.x, bm = blockIdx.y;
  const int m0 = bm * 128, n0 = bn * 128;
  const int tn = t & 15, tm = t >> 4;     // lanes consecutive in tn -> coalesced C
  float acc[8][8];
  #pragma unroll
  for (int i = 0; i < 8; ++i)
    #pragma unroll
    for (int j = 0; j < 8; ++j) acc[i][j] = 0.f;

  const int n4 = m0 >> 12;        // batch of this M-tile (128 | 4096 so uniform)
  const int hw0 = m0 & 4095;

  for (int kt = 0; kt < 256; kt += 32) {
    if (AMODE == 0) {
      #pragma unroll
      for (int r = 0; r < 16; ++r) {
        int idx = t + r * 256;
        int i = idx >> 5, kk = idx & 31;
        As[kk][i] = A[(m0 + i) * 256 + kt + kk];
      }
    } else {
      // x[n][k][h][w]: for fixed k, 128 consecutive hw -> fully coalesced
      #pragma unroll
      for (int r = 0; r < 16; ++r) {
        int idx = t + r * 256;
        int kk = idx >> 7, i = idx & 127;
        As[kk][i] = A[n4 * 1048576 + (kt + kk) * 4096 + hw0 + i];
      }
    }
    #pragma unroll
    for (int r = 0; r < 16; ++r) {
      int idx = t + r * 256;
      int kk = idx >> 7, j = idx & 127;
      int col = n0 + j;
      Bs[kk][j] = (col < Ncols) ? B[(kt + kk) * Ncols + col] : 0.f;
    }
    __syncthreads();
    #pragma unroll 8
    for (int kk = 0; kk < 32; ++kk) {
      float4 a0 = *(const float4*)&As[kk][tm * 8];
      float4 a1 = *(const float4*)&As[kk][tm * 8 + 4];
      float4 b0 = *(const float4*)&Bs[kk][tn * 8];
      float4 b1 = *(const float4*)&Bs[kk][tn * 8 + 4];
      float av[8] = {a0.x,a0.y,a0.z,a0.w,a1.x,a1.y,a1.z,a1.w};
      float bv[8] = {b0.x,b0.y,b0.z,b0.w,b1.x,b1.y,b1.z,b1.w};
      #pragma unroll
      for (int im = 0; im < 8; ++im)
        #pragma unroll
        for (int jn = 0; jn < 8; ++jn)
          acc[im][jn] = fmaf(av[im], bv[jn], acc[im][jn]);
    }
    __syncthreads();
  }

  if (CMODE == 0 || CMODE == 1) {
    #pragma unroll
    for (int im = 0; im < 8; ++im) {
      int p = m0 + tm * 8 + im;
      int rowbase;
      if (CMODE == 0) {
        rowbase = p * Ncols;
      } else {
        int pn = p >> 12, hw = p & 4095, h = hw >> 6, w = hw & 63;
        rowbase = ((pn * HIN + h + 1) * WIN + (w + 1)) * 256;
      }
      #pragma unroll
      for (int j4 = 0; j4 < 8; j4 += 4) {
        int col = n0 + tn * 8 + j4;
        if (col < Ncols) {
          float4 v;
          v.x = acc[im][j4+0] + bias[col+0];
          v.y = acc[im][j4+1] + bias[col+1];
          v.z = acc[im][j4+2] + bias[col+2];
          v.w = acc[im][j4+3] + bias[col+3];
          *(float4*)&C[rowbase + col] = v;
        }
      }
    }
  } else {
    // CMODE 2: NCHW out. Per 32-channel chunk: acc -> LDS [co_local][m] -> f4 stores
    for (int q = 0; q < 4; ++q) {
      __syncthreads();
      if ((tn >> 2) == q) {
        int tnl = tn & 3;
        #pragma unroll
        for (int jn = 0; jn < 8; ++jn) {
          int co = n0 + (q * 4 + tnl) * 8 + jn;
          #pragma unroll
          for (int im = 0; im < 8; ++im)
            As[tnl * 8 + jn][tm * 8 + im] = acc[im][jn] + bias[co];
        }
      }
      __syncthreads();
      #pragma unroll
      for (int r = 0; r < 4; ++r) {
        int f4i = t + r * 256;          // 0..1023
        int row = f4i >> 5;             // co-local 0..31
        int mc = (f4i & 31) * 4;
        int co = n0 + q * 32 + row;
        float4 v = *(const float4*)&As[row][mc];
        *(float4*)&C[(n4 * 256 + co) * 4096 + hw0 + mc] = v;
      }
    }
  }
}

// ---------------- depthwise 3x3 + bias + LayerNorm(C) + exact GELU ----------
// block = one 32-pixel half-row; LDS conv buffer [32 px][257] (pad kills conflicts)
__global__ __launch_bounds__(256) void dwln_k(
    const float* __restrict__ x, const float* __restrict__ dw_w,
    const float* __restrict__ dw_b, const float* __restrict__ ln_g,
    const float* __restrict__ ln_b, float* __restrict__ x1)
{
  __shared__ float cb[32 * 257];
  __shared__ float ps[8][32], pq[8][32];
  __shared__ float mu_s[32], rs_s[32];
  const int blk = blockIdx.x;            // n*128 + h*2 + half
  const int n4 = blk >> 7;
  const int h = (blk & 127) >> 1;
  const int w0 = (blk & 1) * 32;
  const int t = threadIdx.x;
  const int wl = t & 31;                 // local pixel
  const int cl = t >> 5;                 // 0..7
  const float* xb = x + n4 * 1048576;
  const int wg = w0 + wl;

  for (int ci = 0; ci < 32; ++ci) {
    int c = cl * 32 + ci;
    const float* wp = dw_w + c * 9;
    const float* xc = xb + c * 4096;
    float s = 0.f;
    #pragma unroll
    for (int dh = -1; dh <= 1; ++dh) {
      int hh = h + dh;
      if ((unsigned)hh >= 64u) continue;
      #pragma unroll
      for (int dw = -1; dw <= 1; ++dw) {
        int ww = wg + dw;
        if ((unsigned)ww >= 64u) continue;
        s = fmaf(xc[hh * 64 + ww], wp[(dh + 1) * 3 + (dw + 1)], s);
      }
    }
    cb[wl * 257 + c] = s + dw_b[c];
  }
  __syncthreads();
  {
    float s1 = 0.f, s2 = 0.f;
    int base = wl * 257 + cl * 32;
    #pragma unroll 8
    for (int i = 0; i < 32; ++i) {
      float v = cb[base + i];
      s1 += v; s2 = fmaf(v, v, s2);
    }
    ps[cl][wl] = s1; pq[cl][wl] = s2;
  }
  __syncthreads();
  if (t < 32) {
    float s1 = 0.f, s2 = 0.f;
    #pragma unroll
    for (int j = 0; j < 8; ++j) { s1 += ps[j][t]; s2 += pq[j][t]; }
    float mu = s1 * (1.f / 256.f);
    float var = s2 * (1.f / 256.f) - mu * mu;
    mu_s[t] = mu;
    rs_s[t] = rsqrtf(var + 1e-5f);
  }
  __syncthreads();
  const float gw = ln_g[t], gb = ln_b[t];
  float* outb = x1 + (n4 * 4096 + h * 64 + w0) * 256;
  for (int wi = 0; wi < 32; ++wi) {
    float v = cb[wi * 257 + t];
    float y = fmaf((v - mu_s[wi]) * rs_s[wi], gw, gb);
    float ge = 0.5f * y * (1.f + erff(y * 0.70710678f));
    outb[wi * 256 + t] = ge;
  }
}

// ---------------- deformable sampling: thread per (pixel, group) ------------
__global__ __launch_bounds__(256) void sample_k(
    const float* __restrict__ xp, const float* __restrict__ offs,
    const float* __restrict__ mlog, float* __restrict__ samp)
{
  const int tid = blockIdx.x * 256 + threadIdx.x;   // 262144
  const int g = tid & 15;
  const int pix = tid >> 4;
  const int n4 = pix >> 12;
  const int hw = pix & 4095;
  const int h = hw >> 6, w = hw & 63;

  float mk[9];
  {
    const float* mp = mlog + pix * 144 + g * 9;
    float mx = -1e30f;
    #pragma unroll
    for (int p = 0; p < 9; ++p) { mk[p] = mp[p]; mx = fmaxf(mx, mk[p]); }
    float se = 0.f;
    #pragma unroll
    for (int p = 0; p < 9; ++p) { mk[p] = __expf(mk[p] - mx); se += mk[p]; }
    float inv = 1.f / se;
    #pragma unroll
    for (int p = 0; p < 9; ++p) mk[p] *= inv;
  }

  const float* op = offs + pix * 288 + g * 18;
  const float* xpg = xp + (g << 4);
  float ax[16];
  #pragma unroll
  for (int i = 0; i < 16; ++i) ax[i] = 0.f;

  auto corner = [&](int iy, int ix, float wt) {
    if ((unsigned)iy >= (unsigned)HIN || (unsigned)ix >= (unsigned)WIN) return;
    const float* src = xpg + ((n4 * HIN + iy) * WIN + ix) * 256;
    #pragma unroll
    for (int r = 0; r < 4; ++r) {
      float4 s = *(const float4*)(src + r * 4);
      ax[r*4+0] = fmaf(wt, s.x, ax[r*4+0]);
      ax[r*4+1] = fmaf(wt, s.y, ax[r*4+1]);
      ax[r*4+2] = fmaf(wt, s.z, ax[r*4+2]);
      ax[r*4+3] = fmaf(wt, s.w, ax[r*4+3]);
    }
  };

  #pragma unroll
  for (int p = 0; p < 9; ++p) {
    float ox = op[2 * p], oy = op[2 * p + 1];
    // px = w + 1 + (p/3 - 1) + off_x ; py = h + 1 + (p%3 - 1) + off_y
    float px = (float)(w + p / 3) + ox;
    float py = (float)(h + p % 3) + oy;
    float xf = floorf(px), yf = floorf(py);
    float wx = px - xf, wy = py - yf;
    int ix = (int)xf, iy = (int)yf;
    float m = mk[p];
    corner(iy,     ix,     (1.f - wy) * (1.f - wx) * m);
    corner(iy,     ix + 1, (1.f - wy) * wx * m);
    corner(iy + 1, ix,     wy * (1.f - wx) * m);
    corner(iy + 1, ix + 1, wy * wx * m);
  }

  float4* d4 = (float4*)(samp + pix * 256 + (g << 4));
  d4[0] = make_float4(ax[0],  ax[1],  ax[2],  ax[3]);
  d4[1] = make_float4(ax[4],  ax[5],  ax[6],  ax[7]);
  d4[2] = make_float4(ax[8],  ax[9],  ax[10], ax[11]);
  d4[3] = make_float4(ax[12], ax[13], ax[14], ax[15]);
}

extern "C" void kernel_launch(void* const* d_in, const int* in_sizes, int n_in,
                              void* d_out, int out_size, void* d_ws, size_t ws_size,
                              hipStream_t stream) {
  const float* x      = (const float*)d_in[0];
  const float* dw_w   = (const float*)d_in[1];
  const float* dw_b   = (const float*)d_in[2];
  const float* ln_g   = (const float*)d_in[3];
  const float* ln_b   = (const float*)d_in[4];
  const float* off_w  = (const float*)d_in[5];
  const float* off_b  = (const float*)d_in[6];
  const float* mask_w = (const float*)d_in[7];
  const float* mask_b = (const float*)d_in[8];
  const float* inp_w  = (const float*)d_in[9];
  const float* inp_b  = (const float*)d_in[10];
  const float* out_w  = (const float*)d_in[11];
  const float* out_b  = (const float*)d_in[12];
  float* out = (float*)d_out;

  float* xp   = (float*)d_ws;          // 4*66*66*256 = 4,460,544
  float* x1   = xp + 4460544;          // 16384*256   = 4,194,304
  float* offs = x1 + 4194304;          // 16384*288   = 4,718,592
  float* mlog = offs + 4718592;        // 16384*144   = 2,359,296
  float* samp = mlog + 2359296;        // 16384*256   = 4,194,304
  if (ws_size < (size_t)19927040 * 4) return;   // needs ~76 MB scratch

  zero_f4<<<4356, 256, 0, stream>>>((float4*)xp, 1115136);
  gemm_k<1,1><<<dim3(2, 128), 256, 0, stream>>>(x, inp_w, inp_b, xp, 256);
  dwln_k<<<512, 256, 0, stream>>>(x, dw_w, dw_b, ln_g, ln_b, x1);
  gemm_k<0,0><<<dim3(3, 128), 256, 0, stream>>>(x1, off_w, off_b, offs, 288);
  gemm_k<0,0><<<dim3(2, 128), 256, 0, stream>>>(x1, mask_w, mask_b, mlog, 144);
  sample_k<<<1024, 256, 0, stream>>>(xp, offs, mlog, samp);
  gemm_k<0,2><<<dim3(2, 128), 256, 0, stream>>>(samp, out_w, out_b, out, 256);
}

// Round 2
// 224.929 us; speedup vs baseline: 2.0893x; 2.0893x over previous
//
#include <hip/hip_runtime.h>
#include <hip/hip_bf16.h>
#include <math.h>

// R2: bf16 MFMA GEMMs + split dwconv/LN. 10 dispatches.
#define HIN 66
#define WIN 66

using bf16x8 = __attribute__((ext_vector_type(8))) short;
using f32x4  = __attribute__((ext_vector_type(4))) float;

#define GLOBAL_AS __attribute__((address_space(1)))
#define LDS_AS    __attribute__((address_space(3)))

static __device__ inline void g2lds16(const void* g, void* l) {
  __builtin_amdgcn_global_load_lds((const GLOBAL_AS int*)g, (LDS_AS int*)l, 16, 0, 0);
}
static __device__ inline unsigned short f2bf(float v) {
  __hip_bfloat16 b = __float2bfloat16(v);
  return *reinterpret_cast<unsigned short*>(&b);
}
static __device__ inline float bf2f(__hip_bfloat16 b) { return __bfloat162float(b); }

// ---------------- zero (ws is poisoned 0xAA; xp border must be 0) -----------
__global__ __launch_bounds__(256) void zero_f4(float4* __restrict__ p, int n) {
  int i = blockIdx.x * 256 + threadIdx.x;
  if (i < n) p[i] = make_float4(0.f, 0.f, 0.f, 0.f);
}

// ---------------- weight prep: W[k][n] fp32 -> Bt[n][k] bf16 (+pad) --------
__global__ __launch_bounds__(256) void prep_k(
    const float* __restrict__ inp_w, const float* __restrict__ off_w,
    const float* __restrict__ off_b, const float* __restrict__ mask_w,
    const float* __restrict__ mask_b, const float* __restrict__ out_w,
    __hip_bfloat16* __restrict__ BtI, __hip_bfloat16* __restrict__ BtOM,
    __hip_bfloat16* __restrict__ BtO, float* __restrict__ bOM)
{
  int b = blockIdx.x, t = threadIdx.x;   // t = k index
  if (b < 256) {
    int n = b;
    BtI[n * 256 + t] = __float2bfloat16(inp_w[t * 256 + n]);
  } else if (b < 768) {
    int n = b - 256;
    float v = 0.f;
    if (n < 288) v = off_w[t * 288 + n];
    else if (n < 432) v = mask_w[t * 144 + (n - 288)];
    BtOM[n * 256 + t] = __float2bfloat16(v);
    if (b == 256) {
      for (int idx = t; idx < 512; idx += 256) {
        float bv = (idx < 288) ? off_b[idx] : ((idx < 432) ? mask_b[idx - 288] : 0.f);
        bOM[idx] = bv;
      }
    }
  } else {
    int n = b - 768;
    BtO[n * 256 + t] = __float2bfloat16(out_w[t * 256 + n]);
  }
}

// ---------------- x NCHW fp32 -> xT [pix][c] bf16 ---------------------------
__global__ __launch_bounds__(256) void xt_k(const float* __restrict__ x,
                                            __hip_bfloat16* __restrict__ xT) {
  __shared__ float tile[32][65];
  const int hw0 = blockIdx.x * 64, c0 = blockIdx.y * 32, n4 = blockIdx.z;
  const int t = threadIdx.x;
  #pragma unroll
  for (int r = 0; r < 8; ++r) {
    int idx = t + r * 256;
    int cl = idx >> 6, wl = idx & 63;
    tile[cl][wl] = x[(size_t)n4 * 1048576 + (size_t)(c0 + cl) * 4096 + hw0 + wl];
  }
  __syncthreads();
  #pragma unroll
  for (int r = 0; r < 2; ++r) {
    int idx = t + r * 256;           // 512 tasks = 64 pix * 8 cquads
    int pixl = idx >> 3, cq = idx & 7;
    unsigned short b0 = f2bf(tile[cq * 4 + 0][pixl]);
    unsigned short b1 = f2bf(tile[cq * 4 + 1][pixl]);
    unsigned short b2 = f2bf(tile[cq * 4 + 2][pixl]);
    unsigned short b3 = f2bf(tile[cq * 4 + 3][pixl]);
    uint2 u;
    u.x = (unsigned)b0 | ((unsigned)b1 << 16);
    u.y = (unsigned)b2 | ((unsigned)b3 << 16);
    *(uint2*)&xT[((size_t)n4 * 4096 + hw0 + pixl) * 256 + c0 + cq * 4] = u;
  }
}

// ---------------- MFMA GEMM: C[16384 x N] = A[16384 x 256] * Bt^T + bias ----
// A bf16 [m][256], Bt bf16 [n][256]. 128x128 tile, BK=32, 4 waves 2x2.
// CMODE 0: fp32 row-major C. 1: fp32 padded-NHWC xp. 2: bf16 row-major C.
template<int CMODE>
__global__ __launch_bounds__(256) void gemm_mfma(
    const __hip_bfloat16* __restrict__ A, const __hip_bfloat16* __restrict__ Bt,
    const float* __restrict__ bias, void* __restrict__ Cv, int ldc, int nstore)
{
  __shared__ short As[4096];   // [128][32] bf16
  __shared__ short Bs[4096];   // [128][32] bf16
  const int t = threadIdx.x;
  const int wave = t >> 6, lane = t & 63;
  const int quad = lane >> 4, lr = lane & 15;
  const int wm = wave >> 1, wn = wave & 1;
  const size_t m0 = (size_t)blockIdx.y * 128;
  const int n0 = blockIdx.x * 128;

  f32x4 acc[4][4];
  #pragma unroll
  for (int i = 0; i < 4; ++i)
    #pragma unroll
    for (int j = 0; j < 4; ++j)
      acc[i][j] = (f32x4){0.f, 0.f, 0.f, 0.f};

  const int srow = wave * 32;
  for (int kt = 0; kt < 256; kt += 32) {
    #pragma unroll
    for (int j = 0; j < 2; ++j) {
      int chunk = j * 64 + lane;
      int row = srow + (chunk >> 2), kq = chunk & 3;
      const __hip_bfloat16* gA = A + (m0 + row) * 256 + kt + kq * 8;
      const __hip_bfloat16* gB = Bt + (size_t)(n0 + row) * 256 + kt + kq * 8;
      g2lds16(gA, (char*)As + wave * 2048 + j * 1024);
      g2lds16(gB, (char*)Bs + wave * 2048 + j * 1024);
    }
    __syncthreads();
    bf16x8 bfv[4];
    #pragma unroll
    for (int ni = 0; ni < 4; ++ni)
      bfv[ni] = *(const bf16x8*)&Bs[(wn * 64 + ni * 16 + lr) * 32 + quad * 8];
    #pragma unroll
    for (int mi = 0; mi < 4; ++mi) {
      bf16x8 af = *(const bf16x8*)&As[(wm * 64 + mi * 16 + lr) * 32 + quad * 8];
      #pragma unroll
      for (int ni = 0; ni < 4; ++ni)
        acc[mi][ni] = __builtin_amdgcn_mfma_f32_16x16x32_bf16(af, bfv[ni], acc[mi][ni], 0, 0, 0);
    }
    __syncthreads();
  }

  #pragma unroll
  for (int mi = 0; mi < 4; ++mi) {
    #pragma unroll
    for (int ni = 0; ni < 4; ++ni) {
      int col = n0 + wn * 64 + ni * 16 + lr;
      float bv = (col < nstore) ? bias[col] : 0.f;
      #pragma unroll
      for (int reg = 0; reg < 4; ++reg) {
        size_t m = m0 + wm * 64 + mi * 16 + quad * 4 + reg;
        float v = acc[mi][ni][reg] + bv;
        if (CMODE == 0) {
          if (col < nstore) ((float*)Cv)[m * ldc + col] = v;
        } else if (CMODE == 2) {
          if (col < nstore) ((__hip_bfloat16*)Cv)[m * ldc + col] = __float2bfloat16(v);
        } else {
          int pn = (int)(m >> 12), hw = (int)(m & 4095);
          int h = hw >> 6, w = hw & 63;
          ((float*)Cv)[((size_t)(pn * HIN + h + 1) * WIN + (w + 1)) * 256 + col] = v;
        }
      }
    }
  }
}

// ---------------- depthwise 3x3: block per (n,c) plane, NCHW -> NCHW --------
__global__ __launch_bounds__(256) void dwconv_k(
    const float* __restrict__ x, const float* __restrict__ dw_w,
    const float* __restrict__ dw_b, float* __restrict__ y)
{
  __shared__ float pl[4096];            // 64x64 plane
  const int bc = blockIdx.x;
  const int n4 = bc >> 8, c = bc & 255;
  const int t = threadIdx.x;
  const float* xc = x + (size_t)n4 * 1048576 + (size_t)c * 4096;
  #pragma unroll
  for (int r = 0; r < 4; ++r) {
    int idx4 = t + r * 256;
    *(float4*)&pl[idx4 * 4] = *(const float4*)&xc[idx4 * 4];
  }
  float wv[9];
  #pragma unroll
  for (int i = 0; i < 9; ++i) wv[i] = dw_w[c * 9 + i];
  const float bb = dw_b[c];
  __syncthreads();
  float* yc = y + (size_t)(n4 * 256 + c) * 4096;
  #pragma unroll 4
  for (int r = 0; r < 16; ++r) {
    int px = t + r * 256;
    int h = px >> 6, w = px & 63;
    float s = bb;
    #pragma unroll
    for (int dh = -1; dh <= 1; ++dh) {
      int hh = h + dh;
      if ((unsigned)hh >= 64u) continue;
      #pragma unroll
      for (int dw = -1; dw <= 1; ++dw) {
        int ww = w + dw;
        if ((unsigned)ww >= 64u) continue;
        s = fmaf(pl[hh * 64 + ww], wv[(dh + 1) * 3 + (dw + 1)], s);
      }
    }
    yc[px] = s;
  }
}

// ---------------- LayerNorm(C) + GELU: y NCHW -> x1 bf16 [pix][c] -----------
__global__ __launch_bounds__(256) void ln_k(
    const float* __restrict__ y, const float* __restrict__ ln_g,
    const float* __restrict__ ln_b, __hip_bfloat16* __restrict__ x1)
{
  __shared__ float ps[4][64], pq[4][64], mu_s[64], rs_s[64];
  __shared__ unsigned short st[256 * 65];
  const int blk = blockIdx.x;
  const int n4 = blk >> 6, h = blk & 63;
  const int t = threadIdx.x;
  const int w = t & 63, cq = t >> 6;
  const float* yb = y + (size_t)n4 * 1048576 + h * 64 + w;
  float v[64];
  float s1 = 0.f, s2 = 0.f;
  #pragma unroll
  for (int i = 0; i < 64; ++i) {
    v[i] = yb[(size_t)(cq * 64 + i) * 4096];
    s1 += v[i];
    s2 = fmaf(v[i], v[i], s2);
  }
  ps[cq][w] = s1; pq[cq][w] = s2;
  __syncthreads();
  if (t < 64) {
    float a = ps[0][t] + ps[1][t] + ps[2][t] + ps[3][t];
    float b = pq[0][t] + pq[1][t] + pq[2][t] + pq[3][t];
    float mu = a * (1.f / 256.f);
    mu_s[t] = mu;
    rs_s[t] = rsqrtf(b * (1.f / 256.f) - mu * mu + 1e-5f);
  }
  __syncthreads();
  const float mu = mu_s[w], rs = rs_s[w];
  #pragma unroll
  for (int i = 0; i < 64; ++i) {
    int c = cq * 64 + i;
    float yv = fmaf((v[i] - mu) * rs, ln_g[c], ln_b[c]);
    float ge = 0.5f * yv * (1.f + erff(yv * 0.70710678f));
    st[c * 65 + w] = f2bf(ge);
  }
  __syncthreads();
  const size_t row0 = (size_t)n4 * 4096 + (size_t)h * 64;
  #pragma unroll
  for (int r = 0; r < 16; ++r) {
    int idx = t + r * 256;               // 4096 = 64 pix * 64 cquads
    int pix = idx >> 6, cq4 = idx & 63;
    unsigned short b0 = st[(cq4 * 4 + 0) * 65 + pix];
    unsigned short b1 = st[(cq4 * 4 + 1) * 65 + pix];
    unsigned short b2 = st[(cq4 * 4 + 2) * 65 + pix];
    unsigned short b3 = st[(cq4 * 4 + 3) * 65 + pix];
    uint2 u;
    u.x = (unsigned)b0 | ((unsigned)b1 << 16);
    u.y = (unsigned)b2 | ((unsigned)b3 << 16);
    *(uint2*)&x1[(row0 + pix) * 256 + cq4 * 4] = u;
  }
}

// ---------------- deformable sampling (om bf16 in, samp bf16 out) -----------
__global__ __launch_bounds__(256) void sample_k(
    const float* __restrict__ xp, const __hip_bfloat16* __restrict__ om,
    __hip_bfloat16* __restrict__ samp)
{
  const int tid = blockIdx.x * 256 + threadIdx.x;   // 262144
  const int g = tid & 15;
  const int pix = tid >> 4;
  const int n4 = pix >> 12;
  const int hw = pix & 4095;
  const int h = hw >> 6, w = hw & 63;

  float mk[9];
  {
    const __hip_bfloat16* mp = om + (size_t)pix * 448 + 288 + g * 9;
    float mx = -1e30f;
    #pragma unroll
    for (int p = 0; p < 9; ++p) { mk[p] = bf2f(mp[p]); mx = fmaxf(mx, mk[p]); }
    float se = 0.f;
    #pragma unroll
    for (int p = 0; p < 9; ++p) { mk[p] = __expf(mk[p] - mx); se += mk[p]; }
    float inv = 1.f / se;
    #pragma unroll
    for (int p = 0; p < 9; ++p) mk[p] *= inv;
  }

  const __hip_bfloat16* op = om + (size_t)pix * 448 + g * 18;
  const float* xpg = xp + (g << 4);
  float ax[16];
  #pragma unroll
  for (int i = 0; i < 16; ++i) ax[i] = 0.f;

  auto corner = [&](int iy, int ix, float wt) {
    if ((unsigned)iy >= (unsigned)HIN || (unsigned)ix >= (unsigned)WIN) return;
    const float* src = xpg + ((size_t)(n4 * HIN + iy) * WIN + ix) * 256;
    #pragma unroll
    for (int r = 0; r < 4; ++r) {
      float4 s = *(const float4*)(src + r * 4);
      ax[r*4+0] = fmaf(wt, s.x, ax[r*4+0]);
      ax[r*4+1] = fmaf(wt, s.y, ax[r*4+1]);
      ax[r*4+2] = fmaf(wt, s.z, ax[r*4+2]);
      ax[r*4+3] = fmaf(wt, s.w, ax[r*4+3]);
    }
  };

  #pragma unroll
  for (int p = 0; p < 9; ++p) {
    float ox = bf2f(op[2 * p]), oy = bf2f(op[2 * p + 1]);
    float px = (float)(w + p / 3) + ox;
    float py = (float)(h + p % 3) + oy;
    float xf = floorf(px), yf = floorf(py);
    float wx = px - xf, wy = py - yf;
    int ix = (int)xf, iy = (int)yf;
    float m = mk[p];
    corner(iy,     ix,     (1.f - wy) * (1.f - wx) * m);
    corner(iy,     ix + 1, (1.f - wy) * wx * m);
    corner(iy + 1, ix,     wy * (1.f - wx) * m);
    corner(iy + 1, ix + 1, wy * wx * m);
  }

  unsigned short ub[16];
  #pragma unroll
  for (int i = 0; i < 16; ++i) ub[i] = f2bf(ax[i]);
  uint4* d4 = (uint4*)(samp + (size_t)pix * 256 + (g << 4));
  uint4 u0, u1;
  u0.x = (unsigned)ub[0] | ((unsigned)ub[1] << 16);
  u0.y = (unsigned)ub[2] | ((unsigned)ub[3] << 16);
  u0.z = (unsigned)ub[4] | ((unsigned)ub[5] << 16);
  u0.w = (unsigned)ub[6] | ((unsigned)ub[7] << 16);
  u1.x = (unsigned)ub[8] | ((unsigned)ub[9] << 16);
  u1.y = (unsigned)ub[10] | ((unsigned)ub[11] << 16);
  u1.z = (unsigned)ub[12] | ((unsigned)ub[13] << 16);
  u1.w = (unsigned)ub[14] | ((unsigned)ub[15] << 16);
  d4[0] = u0; d4[1] = u1;
}

// ---------------- Cs [pix][c] fp32 -> out NCHW ------------------------------
__global__ __launch_bounds__(256) void outt_k(const float* __restrict__ Cs,
                                              float* __restrict__ out) {
  __shared__ float tile[32][65];
  const int hw0 = blockIdx.x * 64, c0 = blockIdx.y * 32, n4 = blockIdx.z;
  const int t = threadIdx.x;
  #pragma unroll
  for (int r = 0; r < 8; ++r) {
    int idx = t + r * 256;               // 2048 = 64 pix * 32 c
    int pixl = idx >> 5, cl = idx & 31;
    tile[cl][pixl] = Cs[((size_t)n4 * 4096 + hw0 + pixl) * 256 + c0 + cl];
  }
  __syncthreads();
  #pragma unroll
  for (int r = 0; r < 2; ++r) {
    int idx = t + r * 256;               // 512 = 32 c * 16 w-quads
    int cl = idx >> 4, w4 = (idx & 15) * 4;
    float4 v;
    v.x = tile[cl][w4 + 0];
    v.y = tile[cl][w4 + 1];
    v.z = tile[cl][w4 + 2];
    v.w = tile[cl][w4 + 3];
    *(float4*)&out[(size_t)(n4 * 256 + c0 + cl) * 4096 + hw0 + w4] = v;
  }
}

extern "C" void kernel_launch(void* const* d_in, const int* in_sizes, int n_in,
                              void* d_out, int out_size, void* d_ws, size_t ws_size,
                              hipStream_t stream) {
  const float* x      = (const float*)d_in[0];
  const float* dw_w   = (const float*)d_in[1];
  const float* dw_b   = (const float*)d_in[2];
  const float* ln_g   = (const float*)d_in[3];
  const float* ln_b   = (const float*)d_in[4];
  const float* off_w  = (const float*)d_in[5];
  const float* off_b  = (const float*)d_in[6];
  const float* mask_w = (const float*)d_in[7];
  const float* mask_b = (const float*)d_in[8];
  const float* inp_w  = (const float*)d_in[9];
  const float* inp_b  = (const float*)d_in[10];
  const float* out_w  = (const float*)d_in[11];
  const float* out_b  = (const float*)d_in[12];
  float* out = (float*)d_out;

  char* w0 = (char*)d_ws;
  float*           xp   = (float*)(w0);                       // 17,842,176 B
  float*           y    = (float*)(w0 + 17842176);            // 16,777,216 B
  float*           Cs   = y;                                  // alias (y dead)
  __hip_bfloat16*  x1   = (__hip_bfloat16*)(w0 + 34619392);   //  8,388,608 B
  __hip_bfloat16*  xT   = (__hip_bfloat16*)(w0 + 43008000);   //  8,388,608 B
  __hip_bfloat16*  samp = xT;                                 // alias (xT dead)
  __hip_bfloat16*  om   = (__hip_bfloat16*)(w0 + 51396608);   // 14,680,064 B
  __hip_bfloat16*  BtI  = (__hip_bfloat16*)(w0 + 66076672);   //    131,072 B
  __hip_bfloat16*  BtOM = (__hip_bfloat16*)(w0 + 66207744);   //    262,144 B
  __hip_bfloat16*  BtO  = (__hip_bfloat16*)(w0 + 66469888);   //    131,072 B
  float*           bOM  = (float*)(w0 + 66600960);            //      2,048 B
  if (ws_size < 66603008) return;

  zero_f4<<<4356, 256, 0, stream>>>((float4*)xp, 1115136);
  prep_k<<<1024, 256, 0, stream>>>(inp_w, off_w, off_b, mask_w, mask_b, out_w,
                                   BtI, BtOM, BtO, bOM);
  xt_k<<<dim3(64, 8, 4), 256, 0, stream>>>(x, xT);
  gemm_mfma<1><<<dim3(2, 128), 256, 0, stream>>>(xT, BtI, inp_b, xp, 256, 256);
  dwconv_k<<<1024, 256, 0, stream>>>(x, dw_w, dw_b, y);
  ln_k<<<256, 256, 0, stream>>>(y, ln_g, ln_b, x1);
  gemm_mfma<2><<<dim3(4, 128), 256, 0, stream>>>(x1, BtOM, bOM, om, 448, 432);
  sample_k<<<1024, 256, 0, stream>>>(xp, om, samp);
  gemm_mfma<0><<<dim3(2, 128), 256, 0, stream>>>(samp, BtO, out_b, Cs, 256, 256);
  outt_k<<<dim3(64, 8, 4), 256, 0, stream>>>(Cs, out);
}

// Round 3
// 181.895 us; speedup vs baseline: 2.5836x; 1.2366x over previous
//
#include <hip/hip_runtime.h>
#include <hip/hip_bf16.h>
#include <math.h>

// R3: swizzled sampler + bf16 unpadded xpu + fused NCHW epilogue. 8 dispatches.

using bf16x8 = __attribute__((ext_vector_type(8))) short;
using f32x4  = __attribute__((ext_vector_type(4))) float;

#define GLOBAL_AS __attribute__((address_space(1)))
#define LDS_AS    __attribute__((address_space(3)))

static __device__ inline void g2lds16(const void* g, void* l) {
  __builtin_amdgcn_global_load_lds((const GLOBAL_AS int*)g, (LDS_AS int*)l, 16, 0, 0);
}
static __device__ inline unsigned short f2bf(float v) {
  __hip_bfloat16 b = __float2bfloat16(v);
  return *reinterpret_cast<unsigned short*>(&b);
}
static __device__ inline float us2f(unsigned short u) {
  union { unsigned u; float f; } c; c.u = ((unsigned)u) << 16; return c.f;
}

// ---------------- weight prep: W[k][n] fp32 -> Bt[n][k] bf16 (+pad) ---------
__global__ __launch_bounds__(256) void prep_k(
    const float* __restrict__ inp_w, const float* __restrict__ off_w,
    const float* __restrict__ off_b, const float* __restrict__ mask_w,
    const float* __restrict__ mask_b, const float* __restrict__ out_w,
    __hip_bfloat16* __restrict__ BtI, __hip_bfloat16* __restrict__ BtOM,
    __hip_bfloat16* __restrict__ BtO, float* __restrict__ bOM)
{
  int b = blockIdx.x, t = threadIdx.x;   // t = k index
  if (b < 256) {
    int n = b;
    BtI[n * 256 + t] = __float2bfloat16(inp_w[t * 256 + n]);
  } else if (b < 768) {
    int n = b - 256;
    float v = 0.f;
    if (n < 288) v = off_w[t * 288 + n];
    else if (n < 432) v = mask_w[t * 144 + (n - 288)];
    BtOM[n * 256 + t] = __float2bfloat16(v);
    if (b == 256) {
      for (int idx = t; idx < 512; idx += 256) {
        float bv = (idx < 288) ? off_b[idx] : ((idx < 432) ? mask_b[idx - 288] : 0.f);
        bOM[idx] = bv;
      }
    }
  } else {
    int n = b - 768;
    BtO[n * 256 + t] = __float2bfloat16(out_w[t * 256 + n]);
  }
}

// ---------------- x NCHW fp32 -> xT [pix][c] bf16 ---------------------------
__global__ __launch_bounds__(256) void xt_k(const float* __restrict__ x,
                                            __hip_bfloat16* __restrict__ xT) {
  __shared__ float tile[32][65];
  const int hw0 = blockIdx.x * 64, c0 = blockIdx.y * 32, n4 = blockIdx.z;
  const int t = threadIdx.x;
  #pragma unroll
  for (int r = 0; r < 8; ++r) {
    int idx = t + r * 256;
    int cl = idx >> 6, wl = idx & 63;
    tile[cl][wl] = x[(size_t)n4 * 1048576 + (size_t)(c0 + cl) * 4096 + hw0 + wl];
  }
  __syncthreads();
  #pragma unroll
  for (int r = 0; r < 2; ++r) {
    int idx = t + r * 256;           // 512 tasks = 64 pix * 8 cquads
    int pixl = idx >> 3, cq = idx & 7;
    unsigned short b0 = f2bf(tile[cq * 4 + 0][pixl]);
    unsigned short b1 = f2bf(tile[cq * 4 + 1][pixl]);
    unsigned short b2 = f2bf(tile[cq * 4 + 2][pixl]);
    unsigned short b3 = f2bf(tile[cq * 4 + 3][pixl]);
    uint2 u;
    u.x = (unsigned)b0 | ((unsigned)b1 << 16);
    u.y = (unsigned)b2 | ((unsigned)b3 << 16);
    *(uint2*)&xT[((size_t)n4 * 4096 + hw0 + pixl) * 256 + c0 + cq * 4] = u;
  }
}

// ---------------- MFMA GEMM: C[16384 x N] = A[16384 x 256] * Bt^T + bias ----
// A bf16 [m][256], Bt bf16 [n][256]. 128x128 tile, BK=32, 4 waves 2x2.
// CMODE 2: bf16 row-major C (ldc, nstore). CMODE 3: fp32 NCHW out.
template<int CMODE>
__global__ __launch_bounds__(256) void gemm_mfma(
    const __hip_bfloat16* __restrict__ A, const __hip_bfloat16* __restrict__ Bt,
    const float* __restrict__ bias, void* __restrict__ Cv, int ldc, int nstore)
{
  __shared__ __align__(16) char smem[16512];
  short* As = (short*)smem;            // [128][32] bf16 = 8192 B
  short* Bs = (short*)(smem + 8192);   // [128][32] bf16 = 8192 B
  float* tb = (float*)smem;            // CMODE 3 epilogue: [32][129]
  const int t = threadIdx.x;
  const int wave = t >> 6, lane = t & 63;
  const int quad = lane >> 4, lr = lane & 15;
  const int wm = wave >> 1, wn = wave & 1;
  const size_t m0 = (size_t)blockIdx.y * 128;
  const int n0 = blockIdx.x * 128;

  f32x4 acc[4][4];
  #pragma unroll
  for (int i = 0; i < 4; ++i)
    #pragma unroll
    for (int j = 0; j < 4; ++j)
      acc[i][j] = (f32x4){0.f, 0.f, 0.f, 0.f};

  const int srow = wave * 32;
  for (int kt = 0; kt < 256; kt += 32) {
    #pragma unroll
    for (int j = 0; j < 2; ++j) {
      int chunk = j * 64 + lane;
      int row = srow + (chunk >> 2), kq = chunk & 3;
      const __hip_bfloat16* gA = A + (m0 + row) * 256 + kt + kq * 8;
      const __hip_bfloat16* gB = Bt + (size_t)(n0 + row) * 256 + kt + kq * 8;
      g2lds16(gA, (char*)As + wave * 2048 + j * 1024);
      g2lds16(gB, (char*)Bs + wave * 2048 + j * 1024);
    }
    __syncthreads();
    bf16x8 bfv[4];
    #pragma unroll
    for (int ni = 0; ni < 4; ++ni)
      bfv[ni] = *(const bf16x8*)&Bs[(wn * 64 + ni * 16 + lr) * 32 + quad * 8];
    #pragma unroll
    for (int mi = 0; mi < 4; ++mi) {
      bf16x8 af = *(const bf16x8*)&As[(wm * 64 + mi * 16 + lr) * 32 + quad * 8];
      #pragma unroll
      for (int ni = 0; ni < 4; ++ni)
        acc[mi][ni] = __builtin_amdgcn_mfma_f32_16x16x32_bf16(af, bfv[ni], acc[mi][ni], 0, 0, 0);
    }
    __syncthreads();
  }

  if (CMODE == 2) {
    #pragma unroll
    for (int mi = 0; mi < 4; ++mi) {
      #pragma unroll
      for (int ni = 0; ni < 4; ++ni) {
        int col = n0 + wn * 64 + ni * 16 + lr;
        if (col < nstore) {
          float bv = bias[col];
          #pragma unroll
          for (int reg = 0; reg < 4; ++reg) {
            size_t m = m0 + wm * 64 + mi * 16 + quad * 4 + reg;
            ((__hip_bfloat16*)Cv)[m * ldc + col] =
                __float2bfloat16(acc[mi][ni][reg] + bv);
          }
        }
      }
    }
  } else {
    const int n4 = (int)(m0 >> 12), hw0 = (int)(m0 & 4095);
    for (int qc = 0; qc < 4; ++qc) {
      __syncthreads();
      if (wn == (qc >> 1)) {
        #pragma unroll
        for (int nis = 0; nis < 2; ++nis) {
          int ni = 2 * (qc & 1) + nis;
          int col = n0 + wn * 64 + ni * 16 + lr;
          float bv = bias[col];
          int cl = nis * 16 + lr;
          #pragma unroll
          for (int mi = 0; mi < 4; ++mi)
            #pragma unroll
            for (int reg = 0; reg < 4; ++reg) {
              int ml = wm * 64 + mi * 16 + quad * 4 + reg;
              tb[cl * 129 + ml] = acc[mi][ni][reg] + bv;
            }
        }
      }
      __syncthreads();
      #pragma unroll
      for (int r = 0; r < 4; ++r) {
        int f4i = t + r * 256;
        int row = f4i >> 5, mc = (f4i & 31) * 4;
        int co = n0 + qc * 32 + row;
        float4 v;
        v.x = tb[row * 129 + mc + 0];
        v.y = tb[row * 129 + mc + 1];
        v.z = tb[row * 129 + mc + 2];
        v.w = tb[row * 129 + mc + 3];
        *(float4*)&((float*)Cv)[(size_t)(n4 * 256 + co) * 4096 + hw0 + mc] = v;
      }
    }
  }
}

// ---------------- depthwise 3x3: block per (n,c) plane, NCHW -> NCHW --------
__global__ __launch_bounds__(256) void dwconv_k(
    const float* __restrict__ x, const float* __restrict__ dw_w,
    const float* __restrict__ dw_b, float* __restrict__ y)
{
  __shared__ float pl[4096];            // 64x64 plane
  const int bc = blockIdx.x;
  const int n4 = bc >> 8, c = bc & 255;
  const int t = threadIdx.x;
  const float* xc = x + (size_t)n4 * 1048576 + (size_t)c * 4096;
  #pragma unroll
  for (int r = 0; r < 4; ++r) {
    int idx4 = t + r * 256;
    *(float4*)&pl[idx4 * 4] = *(const float4*)&xc[idx4 * 4];
  }
  float wv[9];
  #pragma unroll
  for (int i = 0; i < 9; ++i) wv[i] = dw_w[c * 9 + i];
  const float bb = dw_b[c];
  __syncthreads();
  float* yc = y + (size_t)(n4 * 256 + c) * 4096;
  #pragma unroll 4
  for (int r = 0; r < 16; ++r) {
    int px = t + r * 256;
    int h = px >> 6, w = px & 63;
    float s = bb;
    #pragma unroll
    for (int dh = -1; dh <= 1; ++dh) {
      int hh = h + dh;
      if ((unsigned)hh >= 64u) continue;
      #pragma unroll
      for (int dw = -1; dw <= 1; ++dw) {
        int ww = w + dw;
        if ((unsigned)ww >= 64u) continue;
        s = fmaf(pl[hh * 64 + ww], wv[(dh + 1) * 3 + (dw + 1)], s);
      }
    }
    yc[px] = s;
  }
}

// ---------------- LayerNorm(C) + GELU: y NCHW -> x1 bf16 [pix][c] -----------
__global__ __launch_bounds__(256) void ln_k(
    const float* __restrict__ y, const float* __restrict__ ln_g,
    const float* __restrict__ ln_b, __hip_bfloat16* __restrict__ x1)
{
  __shared__ float ps[4][64], pq[4][64], mu_s[64], rs_s[64];
  __shared__ unsigned short st[256 * 65];
  const int blk = blockIdx.x;
  const int n4 = blk >> 6, h = blk & 63;
  const int t = threadIdx.x;
  const int w = t & 63, cq = t >> 6;
  const float* yb = y + (size_t)n4 * 1048576 + h * 64 + w;
  float v[64];
  float s1 = 0.f, s2 = 0.f;
  #pragma unroll
  for (int i = 0; i < 64; ++i) {
    v[i] = yb[(size_t)(cq * 64 + i) * 4096];
    s1 += v[i];
    s2 = fmaf(v[i], v[i], s2);
  }
  ps[cq][w] = s1; pq[cq][w] = s2;
  __syncthreads();
  if (t < 64) {
    float a = ps[0][t] + ps[1][t] + ps[2][t] + ps[3][t];
    float b = pq[0][t] + pq[1][t] + pq[2][t] + pq[3][t];
    float mu = a * (1.f / 256.f);
    mu_s[t] = mu;
    rs_s[t] = rsqrtf(b * (1.f / 256.f) - mu * mu + 1e-5f);
  }
  __syncthreads();
  const float mu = mu_s[w], rs = rs_s[w];
  #pragma unroll
  for (int i = 0; i < 64; ++i) {
    int c = cq * 64 + i;
    float yv = fmaf((v[i] - mu) * rs, ln_g[c], ln_b[c]);
    float ge = 0.5f * yv * (1.f + erff(yv * 0.70710678f));
    st[c * 65 + w] = f2bf(ge);
  }
  __syncthreads();
  const size_t row0 = (size_t)n4 * 4096 + (size_t)h * 64;
  #pragma unroll
  for (int r = 0; r < 16; ++r) {
    int idx = t + r * 256;               // 4096 = 64 pix * 64 cquads
    int pix = idx >> 6, cq4 = idx & 63;
    unsigned short b0 = st[(cq4 * 4 + 0) * 65 + pix];
    unsigned short b1 = st[(cq4 * 4 + 1) * 65 + pix];
    unsigned short b2 = st[(cq4 * 4 + 2) * 65 + pix];
    unsigned short b3 = st[(cq4 * 4 + 3) * 65 + pix];
    uint2 u;
    u.x = (unsigned)b0 | ((unsigned)b1 << 16);
    u.y = (unsigned)b2 | ((unsigned)b3 << 16);
    *(uint2*)&x1[(row0 + pix) * 256 + cq4 * 4] = u;
  }
}

// ---------------- deformable sampling (swizzled; bf16 xpu; om via LDS) ------
__global__ __launch_bounds__(256) void sample_k(
    const __hip_bfloat16* __restrict__ xpu, const __hip_bfloat16* __restrict__ om,
    __hip_bfloat16* __restrict__ samp)
{
  __shared__ unsigned short oms[16 * 448];   // 14336 B
  const int bid = blockIdx.x;                // 1024
  const int region = bid & 7;                // XCD under round-robin dispatch
  const int q = bid >> 3;                    // 0..127 within region
  const int pix0 = region * 2048 + q * 16;   // 16 consecutive pixels
  const int t = threadIdx.x;

  {  // stage om tile: 16 px * 448 bf16 = 896 uint4
    const uint4* gsrc = (const uint4*)(om + (size_t)pix0 * 448);
    uint4* ldst = (uint4*)oms;
    #pragma unroll
    for (int r = 0; r < 4; ++r) {
      int i = t + r * 256;
      if (i < 896) ldst[i] = gsrc[i];
    }
  }
  __syncthreads();

  const int g = t & 15;
  const int pl = t >> 4;
  const int pix = pix0 + pl;
  const int n4 = pix >> 12;
  const int hw = pix & 4095;
  const int h = hw >> 6, w = hw & 63;

  float mk[9];
  {
    const unsigned short* mp = &oms[pl * 448 + 288 + g * 9];
    float mx = -1e30f;
    #pragma unroll
    for (int p = 0; p < 9; ++p) { mk[p] = us2f(mp[p]); mx = fmaxf(mx, mk[p]); }
    float se = 0.f;
    #pragma unroll
    for (int p = 0; p < 9; ++p) { mk[p] = __expf(mk[p] - mx); se += mk[p]; }
    float inv = 1.f / se;
    #pragma unroll
    for (int p = 0; p < 9; ++p) mk[p] *= inv;
  }

  const unsigned short* op = &oms[pl * 448 + g * 18];
  const __hip_bfloat16* xpg = xpu + (g << 4);
  float ax[16];
  #pragma unroll
  for (int i = 0; i < 16; ++i) ax[i] = 0.f;

  auto corner = [&](int iy, int ix, float wt) {
    // padded coords: data nonzero iff 1<=iy<=64 && 1<=ix<=64
    if ((unsigned)(iy - 1) >= 64u || (unsigned)(ix - 1) >= 64u) return;
    const __hip_bfloat16* src =
        xpg + ((size_t)((n4 << 12) + (iy - 1) * 64 + (ix - 1)) << 8);
    uint4 u0 = *(const uint4*)src;
    uint4 u1 = *(const uint4*)(src + 8);
    const unsigned uu[8] = {u0.x, u0.y, u0.z, u0.w, u1.x, u1.y, u1.z, u1.w};
    #pragma unroll
    for (int i = 0; i < 8; ++i) {
      float lo = us2f((unsigned short)(uu[i] & 0xffff));
      float hi = us2f((unsigned short)(uu[i] >> 16));
      ax[2 * i + 0] = fmaf(wt, lo, ax[2 * i + 0]);
      ax[2 * i + 1] = fmaf(wt, hi, ax[2 * i + 1]);
    }
  };

  #pragma unroll
  for (int p = 0; p < 9; ++p) {
    float ox = us2f(op[2 * p]), oy = us2f(op[2 * p + 1]);
    float px = (float)(w + p / 3) + ox;    // padded-space coords
    float py = (float)(h + p % 3) + oy;
    float xf = floorf(px), yf = floorf(py);
    float wx = px - xf, wy = py - yf;
    int ix = (int)xf, iy = (int)yf;
    float m = mk[p];
    corner(iy,     ix,     (1.f - wy) * (1.f - wx) * m);
    corner(iy,     ix + 1, (1.f - wy) * wx * m);
    corner(iy + 1, ix,     wy * (1.f - wx) * m);
    corner(iy + 1, ix + 1, wy * wx * m);
  }

  unsigned short ub[16];
  #pragma unroll
  for (int i = 0; i < 16; ++i) ub[i] = f2bf(ax[i]);
  uint4* d4 = (uint4*)(samp + (size_t)pix * 256 + (g << 4));
  uint4 u0, u1;
  u0.x = (unsigned)ub[0] | ((unsigned)ub[1] << 16);
  u0.y = (unsigned)ub[2] | ((unsigned)ub[3] << 16);
  u0.z = (unsigned)ub[4] | ((unsigned)ub[5] << 16);
  u0.w = (unsigned)ub[6] | ((unsigned)ub[7] << 16);
  u1.x = (unsigned)ub[8] | ((unsigned)ub[9] << 16);
  u1.y = (unsigned)ub[10] | ((unsigned)ub[11] << 16);
  u1.z = (unsigned)ub[12] | ((unsigned)ub[13] << 16);
  u1.w = (unsigned)ub[14] | ((unsigned)ub[15] << 16);
  d4[0] = u0; d4[1] = u1;
}

extern "C" void kernel_launch(void* const* d_in, const int* in_sizes, int n_in,
                              void* d_out, int out_size, void* d_ws, size_t ws_size,
                              hipStream_t stream) {
  const float* x      = (const float*)d_in[0];
  const float* dw_w   = (const float*)d_in[1];
  const float* dw_b   = (const float*)d_in[2];
  const float* ln_g   = (const float*)d_in[3];
  const float* ln_b   = (const float*)d_in[4];
  const float* off_w  = (const float*)d_in[5];
  const float* off_b  = (const float*)d_in[6];
  const float* mask_w = (const float*)d_in[7];
  const float* mask_b = (const float*)d_in[8];
  const float* inp_w  = (const float*)d_in[9];
  const float* inp_b  = (const float*)d_in[10];
  const float* out_w  = (const float*)d_in[11];
  const float* out_b  = (const float*)d_in[12];
  float* out = (float*)d_out;

  char* w0 = (char*)d_ws;
  __hip_bfloat16* xpu  = (__hip_bfloat16*)(w0);               //  8,388,608 B
  float*          y    = (float*)(w0 + 8388608);              // 16,777,216 B
  __hip_bfloat16* x1   = (__hip_bfloat16*)(w0 + 25165824);    //  8,388,608 B
  __hip_bfloat16* xT   = (__hip_bfloat16*)(w0 + 33554432);    //  8,388,608 B
  __hip_bfloat16* samp = xT;                                  // alias (xT dead)
  __hip_bfloat16* om   = (__hip_bfloat16*)(w0 + 41943040);    // 14,680,064 B
  __hip_bfloat16* BtI  = (__hip_bfloat16*)(w0 + 56623104);    //    131,072 B
  __hip_bfloat16* BtOM = (__hip_bfloat16*)(w0 + 56754176);    //    262,144 B
  __hip_bfloat16* BtO  = (__hip_bfloat16*)(w0 + 57016320);    //    131,072 B
  float*          bOM  = (float*)(w0 + 57147392);             //      2,048 B
  if (ws_size < 57149440) return;

  prep_k<<<1024, 256, 0, stream>>>(inp_w, off_w, off_b, mask_w, mask_b, out_w,
                                   BtI, BtOM, BtO, bOM);
  xt_k<<<dim3(64, 8, 4), 256, 0, stream>>>(x, xT);
  gemm_mfma<2><<<dim3(2, 128), 256, 0, stream>>>(xT, BtI, inp_b, xpu, 256, 256);
  dwconv_k<<<1024, 256, 0, stream>>>(x, dw_w, dw_b, y);
  ln_k<<<256, 256, 0, stream>>>(y, ln_g, ln_b, x1);
  gemm_mfma<2><<<dim3(4, 128), 256, 0, stream>>>(x1, BtOM, bOM, om, 448, 432);
  sample_k<<<1024, 256, 0, stream>>>(xpu, om, samp);
  gemm_mfma<3><<<dim3(2, 128), 256, 0, stream>>>(samp, BtO, out_b, out, 0, 256);
}